// Round 11
// baseline (215.673 us; speedup 1.0000x reference)
//
#include <hip/hip_runtime.h>
#include <math.h>

#define N_ROWS 400      // bs*Q
#define M_ROWS 80       // = 5*16
#define K_CLS  134
#define PN     12544    // = 49*256 selected points (exact!)
#define PFULL  65536    // 256*256
#define WORDS  (PFULL / 32)   // 2048 bitmap words
#define NSUB   25       // 400/16 n-subtiles
#define KCG    49       // rank chunks of 256 (= gemm k-groups)
#define NM     (N_ROWS * M_ROWS)
#define CHUNK  8192     // elements per buildY block
#define CWORDS (CHUNK / 32)      // 256 bitmap words per chunk
#define CPB    (PFULL / CHUNK)   // 8 chunks per row
#define SPAN   192      // staged-word capacity in fused gemm (need ~45)

typedef __attribute__((ext_vector_type(4))) float  f32x4;
typedef __attribute__((ext_vector_type(8))) __bf16 bf16x8;

__device__ __forceinline__ float wave_reduce_sum(float v) {
#pragma unroll
    for (int off = 32; off > 0; off >>= 1) v += __shfl_down(v, off, 64);
    return v;
}

// --- block 0: selection bitmap + per-word rank prefix + chunk-start words
//     cw[kc] (word containing rank 256*kc) + zero accumulators.
//     blocks 1..25: softmax stats (16 rows each, one per wave). ---
__global__ __launch_bounds__(1024) void sort_softmax_kernel(
        const int* __restrict__ point_idx,
        unsigned int* __restrict__ bitmap_g, int* __restrict__ rank_g,
        int* __restrict__ cw_g,
        float* __restrict__ rowS_acc, float* __restrict__ rowSP_acc,
        float* __restrict__ ysum_acc,
        const float* __restrict__ pred_logits,
        float* __restrict__ rowmax, float* __restrict__ rowsum) {
    int tid = threadIdx.x;
    if (blockIdx.x == 0) {
        __shared__ unsigned int bits[WORDS];   // 8 KB
        __shared__ int wtot[16], wbase[16];
        bits[tid] = 0u; bits[tid + 1024] = 0u;
        if (tid < N_ROWS) { rowS_acc[tid] = 0.f; rowSP_acc[tid] = 0.f; }
        if (tid < M_ROWS) ysum_acc[tid] = 0.f;
        __syncthreads();
        for (int i = tid; i < PN; i += 1024) {
            int p = point_idx[i];
            atomicOr(&bits[p >> 5], 1u << (p & 31));
        }
        __syncthreads();
        unsigned int w0 = bits[tid * 2], w1 = bits[tid * 2 + 1];
        int c0 = __popc(w0), c1 = __popc(w1);
        int cnt = c0 + c1;
        int lane = tid & 63, wid = tid >> 6;
        int v = cnt;
#pragma unroll
        for (int off = 1; off < 64; off <<= 1) {
            int u = __shfl_up(v, off, 64);
            if (lane >= off) v += u;
        }
        if (lane == 63) wtot[wid] = v;
        __syncthreads();
        if (tid == 0) {
            int run = 0;
#pragma unroll
            for (int i = 0; i < 16; ++i) { wbase[i] = run; run += wtot[i]; }
        }
        __syncthreads();
        int base = wbase[wid] + (v - cnt);          // exclusive rank before word 2*tid
        bitmap_g[tid * 2]     = w0;
        bitmap_g[tid * 2 + 1] = w1;
        rank_g[tid * 2]       = base;
        rank_g[tid * 2 + 1]   = base + c0;
        // chunk-start words: boundary rank kc*256 falling inside this word
        {
            int rb = base, c = c0, w = tid * 2;
            int kc = (rb + 255) >> 8;
            if (c > 0 && kc < KCG && kc * 256 < rb + c) cw_g[kc] = w;
        }
        {
            int rb = base + c0, c = c1, w = tid * 2 + 1;
            int kc = (rb + 255) >> 8;
            if (c > 0 && kc < KCG && kc * 256 < rb + c) cw_g[kc] = w;
        }
    } else {
        int wave = tid >> 6, lane = tid & 63;
        int n = (blockIdx.x - 1) * 16 + wave;       // < 400
        const float* row = pred_logits + n * K_CLS;
        float mx = -1e30f;
        for (int k = lane; k < K_CLS; k += 64) mx = fmaxf(mx, row[k]);
#pragma unroll
        for (int off = 32; off > 0; off >>= 1) mx = fmaxf(mx, __shfl_down(mx, off, 64));
        mx = __shfl(mx, 0, 64);
        float se = 0.f;
        for (int k = lane; k < K_CLS; k += 64) se += expf(row[k] - mx);
        se = wave_reduce_sum(se);
        if (lane == 0) { rowmax[n] = mx; rowsum[n] = se; }
    }
}

// --- buildY: compact tgt_masks into dense Yc[m][k] bf16 (LDS rank-scatter
//     then dense coalesced stores) + ysum atomics. 640 blocks. ---
__global__ __launch_bounds__(256) void buildY_kernel(
        const float* __restrict__ tgt_masks,
        const unsigned int* __restrict__ bitmap_g, const int* __restrict__ rank_g,
        __bf16* __restrict__ Yc, float* __restrict__ ysum_acc) {
    __shared__ __bf16 comp[CHUNK];            // 16 KB
    __shared__ unsigned int sb[CWORDS];       // 1 KB
    __shared__ int swb[CWORDS];               // 1 KB
    __shared__ float a0[4];
    int b   = blockIdx.x;
    int m = b / CPB, ch = b % CPB;
    int tid = threadIdx.x;
    int wave = tid >> 6, lane = tid & 63;
    int w0  = ch * CWORDS;
    int gb  = rank_g[w0];
    int end = (w0 + CWORDS == WORDS) ? PN : rank_g[w0 + CWORDS];
    int cnt = end - gb;
    sb[tid]  = bitmap_g[w0 + tid];
    swb[tid] = rank_g[w0 + tid] - gb;
    __syncthreads();
    const float* src = tgt_masks + (size_t)m * PFULL + ch * CHUNK;
#pragma unroll
    for (int it = 0; it < CHUNK / (256 * 4); ++it) {
        int e = (it * 256 + tid) * 4;
        f32x4 v = *(const f32x4*)(src + e);
        unsigned int w = sb[e >> 5];
        int bp = e & 31;
        int r0 = swb[e >> 5] + __popc(w & ((1u << bp) - 1u));
        unsigned int m4 = (w >> bp) & 0xFu;
        if (m4 & 1u) comp[r0] = (__bf16)((v[0] > 0.5f) ? 1.f : 0.f);
        if (m4 & 2u) comp[r0 + __popc(m4 & 1u)] = (__bf16)((v[1] > 0.5f) ? 1.f : 0.f);
        if (m4 & 4u) comp[r0 + __popc(m4 & 3u)] = (__bf16)((v[2] > 0.5f) ? 1.f : 0.f);
        if (m4 & 8u) comp[r0 + __popc(m4 & 7u)] = (__bf16)((v[3] > 0.5f) ? 1.f : 0.f);
    }
    __syncthreads();
    __bf16* yrow = Yc + (size_t)m * PN + gb;
    float ys = 0.f;
    for (int i = tid; i < cnt; i += 256) {
        __bf16 y = comp[i];
        yrow[i] = y;
        ys += (float)y;
    }
    ys = wave_reduce_sum(ys);
    if (lane == 0) a0[wave] = ys;
    __syncthreads();
    if (tid == 0)
        atomicAdd(&ysum_acc[m], a0[0] + a0[1] + a0[2] + a0[3]);
}

// --- fused gather+GEMM: block (nsub,kcg) owns ranks [256*kcg, 256*kcg+256).
//     Stage its ~45-word bitmap/rank span; stream the contiguous source
//     slice of its 16 pred_masks rows (each byte read once chip-wide);
//     predicated ds_write scatter of bf16(x) into comp[16][256] (always
//     exactly full: 49*256 == PN); dense sigmoid/softplus on LDS fragments;
//     20 MFMAs. B loads issued up-front (hide under phase 1). Row sums via
//     shfl reduce + one atomicAdd per row. No Xc/Sc round-trip. ---
__global__ __launch_bounds__(256) void gemm_fused_kernel(
        const float* __restrict__ pred_masks,
        const __bf16* __restrict__ Yc,
        const unsigned int* __restrict__ bitmap_g,
        const int* __restrict__ rank_g, const int* __restrict__ cw_g,
        float* __restrict__ xypart, float* __restrict__ sypart,
        float* __restrict__ rowS_acc, float* __restrict__ rowSP_acc) {
    __shared__ __bf16 comp[16 * 272];         // 8.5 KB (pad 272 keeps 16B align)
    __shared__ unsigned int sw[SPAN];         // 768 B
    __shared__ int sr[SPAN];                  // 768 B
    __shared__ float red[4][20][64];          // 20 KB
    __shared__ float rowred[4][2][16];
    int tid = threadIdx.x;
    int wave = tid >> 6, lane = tid & 63;
    int colL = lane & 15, quad = lane >> 4;
    int nsub = blockIdx.x % NSUB, kcg = blockIdx.x / NSUB;  // nsub fastest
    int n0 = nsub * 16;
    int wlo = cw_g[kcg];
    int ew  = (kcg == KCG - 1) ? (WORDS - 1) : cw_g[kcg + 1];
    int S = ew - wlo + 1; if (S > SPAN) S = SPAN;
    int rbase = kcg * 256;
    for (int i = tid; i < S; i += 256) {
        sw[i] = bitmap_g[wlo + i];
        sr[i] = rank_g[wlo + i] - rbase;      // local rank (can be negative)
    }
    // B loads up-front: latency hides under the phase-1 stream
    bf16x8 Bb[2][5];
#pragma unroll
    for (int i = 0; i < 2; ++i) {
        int k0 = kcg * 256 + (wave * 2 + i) * 32 + quad * 8;
#pragma unroll
        for (int j = 0; j < 5; ++j)
            Bb[i][j] = *(const bf16x8*)(Yc + (size_t)(16 * j + colL) * PN + k0);
    }
    __syncthreads();

    // ---- phase 1: scatter bf16(x) to comp[row][local rank] ----
    int E4 = S * 8;                           // f32x4 groups in span
#pragma unroll
    for (int rr = 0; rr < 4; ++rr) {
        int row = wave + rr * 4;              // 0..15
        const float* src = pred_masks + (size_t)(n0 + row) * PFULL + (size_t)wlo * 32;
        __bf16* crow = comp + row * 272;
        for (int e4 = lane; e4 < E4; e4 += 64) {
            f32x4 v = *(const f32x4*)(src + e4 * 4);
            unsigned int w = sw[e4 >> 3];
            int bp = (e4 & 7) * 4;
            int r0 = sr[e4 >> 3] + __popc(w & ((1u << bp) - 1u));
            unsigned int m4 = (w >> bp) & 0xFu;
            int r1 = r0 + (int)(m4 & 1u);
            int r2 = r0 + __popc(m4 & 3u);
            int r3 = r0 + __popc(m4 & 7u);
            if ((m4 & 1u) && (unsigned)r0 < 256u) crow[r0] = (__bf16)v[0];
            if ((m4 & 2u) && (unsigned)r1 < 256u) crow[r1] = (__bf16)v[1];
            if ((m4 & 4u) && (unsigned)r2 < 256u) crow[r2] = (__bf16)v[2];
            if ((m4 & 8u) && (unsigned)r3 < 256u) crow[r3] = (__bf16)v[3];
        }
    }
    __syncthreads();

    // ---- phase 2: A-frags from LDS, sigmoid/softplus, MFMA ----
    f32x4 accX[5], accS[5];
    f32x4 zero = {0.f, 0.f, 0.f, 0.f};
#pragma unroll
    for (int j = 0; j < 5; ++j) { accX[j] = zero; accS[j] = zero; }
    float sS = 0.f, sSP = 0.f;
#pragma unroll
    for (int i = 0; i < 2; ++i) {
        int kl = (wave * 2 + i) * 32 + quad * 8;
        bf16x8 aX = *(const bf16x8*)&comp[colL * 272 + kl];
        bf16x8 aSg;
#pragma unroll
        for (int jj = 0; jj < 8; ++jj) {
            float x  = (float)aX[jj];
            float ax = fabsf(x);
            float ee = __expf(-ax);
            float den = 1.f + ee;
            float inv = __builtin_amdgcn_rcpf(den);
            float sig = (x >= 0.f) ? inv : ee * inv;
            float sp  = fmaxf(x, 0.f) + __logf(den);
            aSg[jj] = (__bf16)sig;
            sS += sig; sSP += sp;
        }
#pragma unroll
        for (int j = 0; j < 5; ++j) {
            accX[j] = __builtin_amdgcn_mfma_f32_16x16x32_bf16(aX,  Bb[i][j], accX[j], 0, 0, 0);
            accS[j] = __builtin_amdgcn_mfma_f32_16x16x32_bf16(aSg, Bb[i][j], accS[j], 0, 0, 0);
        }
    }
    // row sums: lanes {colL, colL+16, colL+32, colL+48} hold row colL's parts
    sS  += __shfl_down(sS, 32, 64);
    sS  += __shfl_down(sS, 16, 64);
    sSP += __shfl_down(sSP, 32, 64);
    sSP += __shfl_down(sSP, 16, 64);
    if (lane < 16) { rowred[wave][0][lane] = sS; rowred[wave][1][lane] = sSP; }

    // ---- epilogue pass 1: xy partials + row-sum atomics ----
#pragma unroll
    for (int j = 0; j < 5; ++j)
#pragma unroll
        for (int r = 0; r < 4; ++r) red[wave][j * 4 + r][lane] = accX[j][r];
    __syncthreads();
#pragma unroll
    for (int v0 = 0; v0 < 5; ++v0) {
        int v = wave * 5 + v0;
        float s = red[0][v][lane] + red[1][v][lane] + red[2][v][lane] + red[3][v][lane];
        int j = v >> 2, r = v & 3;
        int n = n0 + quad * 4 + r, m = 16 * j + colL;   // verified C/D layout
        xypart[(size_t)kcg * NM + n * M_ROWS + m] = s;
    }
    if (tid < 16) {
        atomicAdd(&rowS_acc[n0 + tid],
                  rowred[0][0][tid] + rowred[1][0][tid] +
                  rowred[2][0][tid] + rowred[3][0][tid]);
    } else if (tid < 32) {
        int l = tid - 16;
        atomicAdd(&rowSP_acc[n0 + l],
                  rowred[0][1][l] + rowred[1][1][l] +
                  rowred[2][1][l] + rowred[3][1][l]);
    }
    __syncthreads();
    // ---- epilogue pass 2: sy partials ----
#pragma unroll
    for (int j = 0; j < 5; ++j)
#pragma unroll
        for (int r = 0; r < 4; ++r) red[wave][j * 4 + r][lane] = accS[j][r];
    __syncthreads();
#pragma unroll
    for (int v0 = 0; v0 < 5; ++v0) {
        int v = wave * 5 + v0;
        float s = red[0][v][lane] + red[1][v][lane] + red[2][v][lane] + red[3][v][lane];
        int j = v >> 2, r = v & 3;
        int n = n0 + quad * 4 + r, m = 16 * j + colL;
        sypart[(size_t)kcg * NM + n * M_ROWS + m] = s;
    }
}

// --- combine: reduce 49 xy/sy partials (4 lane-groups) + cost terms. ---
__global__ __launch_bounds__(256) void combine_kernel(
        const float* __restrict__ logits,
        const int* __restrict__ tgt_labels,
        const float* __restrict__ rowmax,
        const float* __restrict__ rowsum,
        const float* __restrict__ rowS_acc,
        const float* __restrict__ rowSP_acc,
        const float* __restrict__ ysum_acc,
        const float* __restrict__ xypart,
        const float* __restrict__ sypart,
        float* __restrict__ out) {
    __shared__ float sxy[4][64], ssy[4][64];
    int il = threadIdx.x & 63, q = threadIdx.x >> 6;
    int idx = blockIdx.x * 64 + il;
    int n = idx / M_ROWS, m = idx % M_ROWS;
    float xy = 0.f, sy = 0.f;
    for (int g = q; g < KCG; g += 4) {
        xy += xypart[(size_t)g * NM + idx];
        sy += sypart[(size_t)g * NM + idx];
    }
    sxy[q][il] = xy; ssy[q][il] = sy;
    __syncthreads();
    if (q == 0) {
        xy = sxy[0][il] + sxy[1][il] + sxy[2][il] + sxy[3][il];
        sy = ssy[0][il] + ssy[1][il] + ssy[2][il] + ssy[3][il];
        float ss = rowS_acc[n], sp = rowSP_acc[n], ysum = ysum_acc[m];
        int tc = tgt_labels[m];
        tc = min(max(tc, 0), K_CLS - 1);
        float p = expf(logits[n * K_CLS + tc] - rowmax[n]) / rowsum[n];
        float cost_class = -p;
        float cost_mask = (sp - xy) * (1.0f / PN);
        float cost_dice = 1.f - (2.f * sy + 1.f) / (ss + ysum + 1.f);
        out[idx] = 2.f * cost_class + 5.f * cost_mask + 5.f * cost_dice;
    }
}

extern "C" void kernel_launch(void* const* d_in, const int* in_sizes, int n_in,
                              void* d_out, int out_size, void* d_ws, size_t ws_size,
                              hipStream_t stream) {
    const float* pred_logits = (const float*)d_in[0];   // (4,100,134)
    const float* pred_masks  = (const float*)d_in[1];   // (4,100,256,256)
    const int*   tgt_labels  = (const int*)d_in[2];     // (80,)
    const float* tgt_masks   = (const float*)d_in[3];   // (80,256,256)
    const int*   point_idx   = (const int*)d_in[4];     // (12544,)
    float* out = (float*)d_out;                         // (4,100,80)

    char* ws = (char*)d_ws;
    size_t off = 0;
    auto carve = [&](size_t nbytes) {
        char* p = ws + off;
        off += (nbytes + 255) & ~(size_t)255;
        return p;
    };
    // accumulators zeroed by sort kernel (stream-ordered before users)
    unsigned int* bitmap = (unsigned int*)carve(WORDS * 4);            // 8 KB
    int*   rankp  = (int*)carve(WORDS * 4);                            // 8 KB
    int*   cw     = (int*)carve(KCG * 4);
    float* rowmax = (float*)carve(N_ROWS * 4);
    float* rowsum = (float*)carve(N_ROWS * 4);
    float* rowS_acc  = (float*)carve(N_ROWS * 4);
    float* rowSP_acc = (float*)carve(N_ROWS * 4);
    float* ysum_acc  = (float*)carve(M_ROWS * 4);
    __bf16* Yc = (__bf16*)carve((size_t)M_ROWS * PN * 2);              // 2.0 MB
    float* xypart = (float*)carve((size_t)KCG * NM * 4);               // 6.3 MB
    float* sypart = (float*)carve((size_t)KCG * NM * 4);               // 6.3 MB
    (void)ws_size; (void)in_sizes; (void)n_in; (void)out_size;

    sort_softmax_kernel<<<26, 1024, 0, stream>>>(
        point_idx, bitmap, rankp, cw, rowS_acc, rowSP_acc, ysum_acc,
        pred_logits, rowmax, rowsum);
    buildY_kernel<<<M_ROWS * CPB, 256, 0, stream>>>(
        tgt_masks, bitmap, rankp, Yc, ysum_acc);
    gemm_fused_kernel<<<NSUB * KCG, 256, 0, stream>>>(
        pred_masks, Yc, bitmap, rankp, cw, xypart, sypart,
        rowS_acc, rowSP_acc);
    combine_kernel<<<NM / 64, 256, 0, stream>>>(
        pred_logits, tgt_labels, rowmax, rowsum, rowS_acc, rowSP_acc,
        ysum_acc, xypart, sypart, out);
}

// Round 14
// 206.813 us; speedup vs baseline: 1.0428x; 1.0428x over previous
//
#include <hip/hip_runtime.h>
#include <math.h>

#define N_ROWS 400      // bs*Q
#define M_ROWS 80       // = 5*16
#define K_CLS  134
#define PN     12544    // = 49*256 selected points (exact!)
#define PFULL  65536    // 256*256
#define WORDS  (PFULL / 32)   // 2048 bitmap words
#define NSUB   25       // 400/16 n-subtiles
#define KCG    49       // rank chunks of 256 (= gemm k-groups)
#define NM     (N_ROWS * M_ROWS)
#define CHUNK  8192     // elements per buildY block
#define CWORDS (CHUNK / 32)      // 256 bitmap words per chunk
#define CPB    (PFULL / CHUNK)   // 8 chunks per row
#define SPAN   64       // staged-word capacity (need ~42+-2.4; 64 = +9 sigma)
#define NIT    8        // SPAN*8/64 fixed phase-1 iterations per row

typedef __attribute__((ext_vector_type(4))) float  f32x4;
typedef __attribute__((ext_vector_type(8))) __bf16 bf16x8;

__device__ __forceinline__ float wave_reduce_sum(float v) {
#pragma unroll
    for (int off = 32; off > 0; off >>= 1) v += __shfl_down(v, off, 64);
    return v;
}

// --- block 0: selection bitmap + per-word rank prefix + chunk-start words
//     cw[kc] (word containing rank 256*kc) + zero accumulators.
//     blocks 1..25: softmax stats (16 rows each, one per wave). ---
__global__ __launch_bounds__(1024) void sort_softmax_kernel(
        const int* __restrict__ point_idx,
        unsigned int* __restrict__ bitmap_g, int* __restrict__ rank_g,
        int* __restrict__ cw_g,
        float* __restrict__ rowS_acc, float* __restrict__ rowSP_acc,
        float* __restrict__ ysum_acc,
        const float* __restrict__ pred_logits,
        float* __restrict__ rowmax, float* __restrict__ rowsum) {
    int tid = threadIdx.x;
    if (blockIdx.x == 0) {
        __shared__ unsigned int bits[WORDS];   // 8 KB
        __shared__ int wtot[16], wbase[16];
        bits[tid] = 0u; bits[tid + 1024] = 0u;
        if (tid < N_ROWS) { rowS_acc[tid] = 0.f; rowSP_acc[tid] = 0.f; }
        if (tid < M_ROWS) ysum_acc[tid] = 0.f;
        __syncthreads();
        for (int i = tid; i < PN; i += 1024) {
            int p = point_idx[i];
            atomicOr(&bits[p >> 5], 1u << (p & 31));
        }
        __syncthreads();
        unsigned int w0 = bits[tid * 2], w1 = bits[tid * 2 + 1];
        int c0 = __popc(w0), c1 = __popc(w1);
        int cnt = c0 + c1;
        int lane = tid & 63, wid = tid >> 6;
        int v = cnt;
#pragma unroll
        for (int off = 1; off < 64; off <<= 1) {
            int u = __shfl_up(v, off, 64);
            if (lane >= off) v += u;
        }
        if (lane == 63) wtot[wid] = v;
        __syncthreads();
        if (tid == 0) {
            int run = 0;
#pragma unroll
            for (int i = 0; i < 16; ++i) { wbase[i] = run; run += wtot[i]; }
        }
        __syncthreads();
        int base = wbase[wid] + (v - cnt);          // exclusive rank before word 2*tid
        bitmap_g[tid * 2]     = w0;
        bitmap_g[tid * 2 + 1] = w1;
        rank_g[tid * 2]       = base;
        rank_g[tid * 2 + 1]   = base + c0;
        // chunk-start words: boundary rank kc*256 falling inside this word
        {
            int rb = base, c = c0, w = tid * 2;
            int kc = (rb + 255) >> 8;
            if (c > 0 && kc < KCG && kc * 256 < rb + c) cw_g[kc] = w;
        }
        {
            int rb = base + c0, c = c1, w = tid * 2 + 1;
            int kc = (rb + 255) >> 8;
            if (c > 0 && kc < KCG && kc * 256 < rb + c) cw_g[kc] = w;
        }
    } else {
        int wave = tid >> 6, lane = tid & 63;
        int n = (blockIdx.x - 1) * 16 + wave;       // < 400
        const float* row = pred_logits + n * K_CLS;
        float mx = -1e30f;
        for (int k = lane; k < K_CLS; k += 64) mx = fmaxf(mx, row[k]);
#pragma unroll
        for (int off = 32; off > 0; off >>= 1) mx = fmaxf(mx, __shfl_down(mx, off, 64));
        mx = __shfl(mx, 0, 64);
        float se = 0.f;
        for (int k = lane; k < K_CLS; k += 64) se += expf(row[k] - mx);
        se = wave_reduce_sum(se);
        if (lane == 0) { rowmax[n] = mx; rowsum[n] = se; }
    }
}

// --- buildY: compact tgt_masks into dense Yc[m][k] bf16. Branch-free
//     LDS rank-scatter (trash-slot redirect, unconditional ds_write). ---
__global__ __launch_bounds__(256) void buildY_kernel(
        const float* __restrict__ tgt_masks,
        const unsigned int* __restrict__ bitmap_g, const int* __restrict__ rank_g,
        __bf16* __restrict__ Yc, float* __restrict__ ysum_acc) {
    __shared__ __bf16 comp[CHUNK + 16];       // 16 KB + trash slots
    __shared__ unsigned int sb[CWORDS];       // 1 KB
    __shared__ int swb[CWORDS];               // 1 KB
    __shared__ float a0[4];
    int b   = blockIdx.x;
    int m = b / CPB, ch = b % CPB;
    int tid = threadIdx.x;
    int wave = tid >> 6, lane = tid & 63;
    int w0  = ch * CWORDS;
    int gb  = rank_g[w0];
    int end = (w0 + CWORDS == WORDS) ? PN : rank_g[w0 + CWORDS];
    int cnt = end - gb;
    sb[tid]  = bitmap_g[w0 + tid];
    swb[tid] = rank_g[w0 + tid] - gb;
    __syncthreads();
    const float* src = tgt_masks + (size_t)m * PFULL + ch * CHUNK;
    int t = CHUNK + (lane & 15);
#pragma unroll
    for (int it = 0; it < CHUNK / (256 * 4); ++it) {
        int e = (it * 256 + tid) * 4;
        f32x4 v = *(const f32x4*)(src + e);
        unsigned int w = sb[e >> 5];
        int bp = e & 31;
        int rb = swb[e >> 5] + __popc(w & ((1u << bp) - 1u));
        unsigned int m4 = (w >> bp) & 0xFu;
        int r0 = (m4 & 1u) ? rb : t;
        int r1 = (m4 & 2u) ? rb + (int)(m4 & 1u) : t;
        int r2 = (m4 & 4u) ? rb + __popc(m4 & 3u) : t;
        int r3 = (m4 & 8u) ? rb + __popc(m4 & 7u) : t;
        comp[r0] = (__bf16)((v[0] > 0.5f) ? 1.f : 0.f);
        comp[r1] = (__bf16)((v[1] > 0.5f) ? 1.f : 0.f);
        comp[r2] = (__bf16)((v[2] > 0.5f) ? 1.f : 0.f);
        comp[r3] = (__bf16)((v[3] > 0.5f) ? 1.f : 0.f);
    }
    __syncthreads();
    __bf16* yrow = Yc + (size_t)m * PN + gb;
    float ys = 0.f;
    for (int i = tid; i < cnt; i += 256) {
        __bf16 y = comp[i];
        yrow[i] = y;
        ys += (float)y;
    }
    ys = wave_reduce_sum(ys);
    if (lane == 0) a0[wave] = ys;
    __syncthreads();
    if (tid == 0)
        atomicAdd(&ysum_acc[m], a0[0] + a0[1] + a0[2] + a0[3]);
}

// --- fused gather+GEMM: branch-free scatter (trash-redirect, unconditional
//     ds_write), fixed 8-iteration fully-unrolled phase 1 with all loads
//     issued up-front (8 KB in flight per wave), LDS aliased (comp/sw/sr
//     reuse red's space; 21 KB total). ---
__global__ __launch_bounds__(256) void gemm_fused_kernel(
        const float* __restrict__ pred_masks,
        const __bf16* __restrict__ Yc,
        const unsigned int* __restrict__ bitmap_g,
        const int* __restrict__ rank_g, const int* __restrict__ cw_g,
        float* __restrict__ xypart, float* __restrict__ sypart,
        float* __restrict__ rowS_acc, float* __restrict__ rowSP_acc) {
    __shared__ __align__(16) unsigned char smem[20992];
    __bf16* comp      = (__bf16*)smem;                 // [16][272] = 8704 B
    unsigned int* sw  = (unsigned int*)(smem + 8704);  // 256 B
    int* sr           = (int*)(smem + 8960);           // 256 B
    float (*red)[20][64] = (float (*)[20][64])smem;    // 20480 B (aliases comp)
    float (*rowred)[2][16] = (float (*)[2][16])(smem + 20480);  // 512 B (no alias)

    int tid = threadIdx.x;
    int wave = tid >> 6, lane = tid & 63;
    int colL = lane & 15, quad = lane >> 4;
    int nsub = blockIdx.x % NSUB, kcg = blockIdx.x / NSUB;  // nsub fastest
    int n0 = nsub * 16;
    int wlo = cw_g[kcg];
    int ew  = (kcg == KCG - 1) ? (WORDS - 1) : cw_g[kcg + 1];
    int S = ew - wlo + 1; if (S > SPAN) S = SPAN;
    int E4 = S * 8;                           // valid f32x4 groups in span
    int rbase = kcg * 256;
    for (int i = tid; i < S; i += 256) {
        sw[i] = bitmap_g[wlo + i];
        sr[i] = rank_g[wlo + i] - rbase;      // local rank (can be negative)
    }
    // B loads up-front: latency hides under the phase-1 stream
    bf16x8 Bb[2][5];
#pragma unroll
    for (int i = 0; i < 2; ++i) {
        int k0 = kcg * 256 + (wave * 2 + i) * 32 + quad * 8;
#pragma unroll
        for (int j = 0; j < 5; ++j)
            Bb[i][j] = *(const bf16x8*)(Yc + (size_t)(16 * j + colL) * PN + k0);
    }
    __syncthreads();

    // ---- phase 1: branch-free scatter bf16(x) -> comp[row][local rank] ----
    int trash = 256 + (lane & 15);
#pragma unroll 1
    for (int rr = 0; rr < 4; ++rr) {
        int row = wave + rr * 4;              // 0..15
        const float* src = pred_masks + (size_t)(n0 + row) * PFULL + (size_t)wlo * 32;
        __bf16* crow = comp + row * 272;
        f32x4 vb[NIT];
#pragma unroll
        for (int it = 0; it < NIT; ++it) {    // all 8 loads issued up-front
            int e4 = lane + it * 64;
            int e4c = (e4 < E4) ? e4 : (E4 - 1);   // clamp: duplicate = idempotent
            vb[it] = *(const f32x4*)(src + (size_t)e4c * 4);
        }
#pragma unroll
        for (int it = 0; it < NIT; ++it) {
            int e4 = lane + it * 64;
            int e4c = (e4 < E4) ? e4 : (E4 - 1);
            unsigned int w = sw[e4c >> 3];
            int bp = (e4c & 7) * 4;
            int rb = sr[e4c >> 3] + __popc(w & ((1u << bp) - 1u));
            unsigned int m4 = (w >> bp) & 0xFu;
            int r0 = rb;
            int r1 = rb + (int)(m4 & 1u);
            int r2 = rb + __popc(m4 & 3u);
            int r3 = rb + __popc(m4 & 7u);
            r0 = ((m4 & 1u) && (unsigned)r0 < 256u) ? r0 : trash;
            r1 = ((m4 & 2u) && (unsigned)r1 < 256u) ? r1 : trash;
            r2 = ((m4 & 4u) && (unsigned)r2 < 256u) ? r2 : trash;
            r3 = ((m4 & 8u) && (unsigned)r3 < 256u) ? r3 : trash;
            crow[r0] = (__bf16)vb[it][0];
            crow[r1] = (__bf16)vb[it][1];
            crow[r2] = (__bf16)vb[it][2];
            crow[r3] = (__bf16)vb[it][3];
        }
    }
    __syncthreads();

    // ---- phase 2: A-frags from LDS, sigmoid/softplus, MFMA ----
    f32x4 accX[5], accS[5];
    f32x4 zero = {0.f, 0.f, 0.f, 0.f};
#pragma unroll
    for (int j = 0; j < 5; ++j) { accX[j] = zero; accS[j] = zero; }
    float sS = 0.f, sSP = 0.f;
#pragma unroll
    for (int i = 0; i < 2; ++i) {
        int kl = (wave * 2 + i) * 32 + quad * 8;
        bf16x8 aX = *(const bf16x8*)&comp[colL * 272 + kl];
        bf16x8 aSg;
#pragma unroll
        for (int jj = 0; jj < 8; ++jj) {
            float x  = (float)aX[jj];
            float ax = fabsf(x);
            float ee = __expf(-ax);
            float den = 1.f + ee;
            float inv = __builtin_amdgcn_rcpf(den);
            float sig = (x >= 0.f) ? inv : ee * inv;
            float sp  = fmaxf(x, 0.f) + __logf(den);
            aSg[jj] = (__bf16)sig;
            sS += sig; sSP += sp;
        }
#pragma unroll
        for (int j = 0; j < 5; ++j) {
            accX[j] = __builtin_amdgcn_mfma_f32_16x16x32_bf16(aX,  Bb[i][j], accX[j], 0, 0, 0);
            accS[j] = __builtin_amdgcn_mfma_f32_16x16x32_bf16(aSg, Bb[i][j], accS[j], 0, 0, 0);
        }
    }
    // row sums: lanes {colL, colL+16, colL+32, colL+48} hold row colL's parts
    sS  += __shfl_down(sS, 32, 64);
    sS  += __shfl_down(sS, 16, 64);
    sSP += __shfl_down(sSP, 32, 64);
    sSP += __shfl_down(sSP, 16, 64);
    if (lane < 16) { rowred[wave][0][lane] = sS; rowred[wave][1][lane] = sSP; }
    __syncthreads();   // all comp reads done -> red may now alias comp

    // ---- epilogue pass 1: xy partials + row-sum atomics ----
#pragma unroll
    for (int j = 0; j < 5; ++j)
#pragma unroll
        for (int r = 0; r < 4; ++r) red[wave][j * 4 + r][lane] = accX[j][r];
    __syncthreads();
#pragma unroll
    for (int v0 = 0; v0 < 5; ++v0) {
        int v = wave * 5 + v0;
        float s = red[0][v][lane] + red[1][v][lane] + red[2][v][lane] + red[3][v][lane];
        int j = v >> 2, r = v & 3;
        int n = n0 + quad * 4 + r, m = 16 * j + colL;   // verified C/D layout
        xypart[(size_t)kcg * NM + n * M_ROWS + m] = s;
    }
    if (tid < 16) {
        atomicAdd(&rowS_acc[n0 + tid],
                  rowred[0][0][tid] + rowred[1][0][tid] +
                  rowred[2][0][tid] + rowred[3][0][tid]);
    } else if (tid < 32) {
        int l = tid - 16;
        atomicAdd(&rowSP_acc[n0 + l],
                  rowred[0][1][l] + rowred[1][1][l] +
                  rowred[2][1][l] + rowred[3][1][l]);
    }
    __syncthreads();
    // ---- epilogue pass 2: sy partials ----
#pragma unroll
    for (int j = 0; j < 5; ++j)
#pragma unroll
        for (int r = 0; r < 4; ++r) red[wave][j * 4 + r][lane] = accS[j][r];
    __syncthreads();
#pragma unroll
    for (int v0 = 0; v0 < 5; ++v0) {
        int v = wave * 5 + v0;
        float s = red[0][v][lane] + red[1][v][lane] + red[2][v][lane] + red[3][v][lane];
        int j = v >> 2, r = v & 3;
        int n = n0 + quad * 4 + r, m = 16 * j + colL;
        sypart[(size_t)kcg * NM + n * M_ROWS + m] = s;
    }
}

// --- combine: reduce 49 xy/sy partials (4 lane-groups) + cost terms. ---
__global__ __launch_bounds__(256) void combine_kernel(
        const float* __restrict__ logits,
        const int* __restrict__ tgt_labels,
        const float* __restrict__ rowmax,
        const float* __restrict__ rowsum,
        const float* __restrict__ rowS_acc,
        const float* __restrict__ rowSP_acc,
        const float* __restrict__ ysum_acc,
        const float* __restrict__ xypart,
        const float* __restrict__ sypart,
        float* __restrict__ out) {
    __shared__ float sxy[4][64], ssy[4][64];
    int il = threadIdx.x & 63, q = threadIdx.x >> 6;
    int idx = blockIdx.x * 64 + il;
    int n = idx / M_ROWS, m = idx % M_ROWS;
    float xy = 0.f, sy = 0.f;
    for (int g = q; g < KCG; g += 4) {
        xy += xypart[(size_t)g * NM + idx];
        sy += sypart[(size_t)g * NM + idx];
    }
    sxy[q][il] = xy; ssy[q][il] = sy;
    __syncthreads();
    if (q == 0) {
        xy = sxy[0][il] + sxy[1][il] + sxy[2][il] + sxy[3][il];
        sy = ssy[0][il] + ssy[1][il] + ssy[2][il] + ssy[3][il];
        float ss = rowS_acc[n], sp = rowSP_acc[n], ysum = ysum_acc[m];
        int tc = tgt_labels[m];
        tc = min(max(tc, 0), K_CLS - 1);
        float p = expf(logits[n * K_CLS + tc] - rowmax[n]) / rowsum[n];
        float cost_class = -p;
        float cost_mask = (sp - xy) * (1.0f / PN);
        float cost_dice = 1.f - (2.f * sy + 1.f) / (ss + ysum + 1.f);
        out[idx] = 2.f * cost_class + 5.f * cost_mask + 5.f * cost_dice;
    }
}

extern "C" void kernel_launch(void* const* d_in, const int* in_sizes, int n_in,
                              void* d_out, int out_size, void* d_ws, size_t ws_size,
                              hipStream_t stream) {
    const float* pred_logits = (const float*)d_in[0];   // (4,100,134)
    const float* pred_masks  = (const float*)d_in[1];   // (4,100,256,256)
    const int*   tgt_labels  = (const int*)d_in[2];     // (80,)
    const float* tgt_masks   = (const float*)d_in[3];   // (80,256,256)
    const int*   point_idx   = (const int*)d_in[4];     // (12544,)
    float* out = (float*)d_out;                         // (4,100,80)

    char* ws = (char*)d_ws;
    size_t off = 0;
    auto carve = [&](size_t nbytes) {
        char* p = ws + off;
        off += (nbytes + 255) & ~(size_t)255;
        return p;
    };
    // accumulators zeroed by sort kernel (stream-ordered before users)
    unsigned int* bitmap = (unsigned int*)carve(WORDS * 4);            // 8 KB
    int*   rankp  = (int*)carve(WORDS * 4);                            // 8 KB
    int*   cw     = (int*)carve(KCG * 4);
    float* rowmax = (float*)carve(N_ROWS * 4);
    float* rowsum = (float*)carve(N_ROWS * 4);
    float* rowS_acc  = (float*)carve(N_ROWS * 4);
    float* rowSP_acc = (float*)carve(N_ROWS * 4);
    float* ysum_acc  = (float*)carve(M_ROWS * 4);
    __bf16* Yc = (__bf16*)carve((size_t)M_ROWS * PN * 2);              // 2.0 MB
    float* xypart = (float*)carve((size_t)KCG * NM * 4);               // 6.3 MB
    float* sypart = (float*)carve((size_t)KCG * NM * 4);               // 6.3 MB
    (void)ws_size; (void)in_sizes; (void)n_in; (void)out_size;

    sort_softmax_kernel<<<26, 1024, 0, stream>>>(
        point_idx, bitmap, rankp, cw, rowS_acc, rowSP_acc, ysum_acc,
        pred_logits, rowmax, rowsum);
    buildY_kernel<<<M_ROWS * CPB, 256, 0, stream>>>(
        tgt_masks, bitmap, rankp, Yc, ysum_acc);
    gemm_fused_kernel<<<NSUB * KCG, 256, 0, stream>>>(
        pred_masks, Yc, bitmap, rankp, cw, xypart, sypart,
        rowS_acc, rowSP_acc);
    combine_kernel<<<NM / 64, 256, 0, stream>>>(
        pred_logits, tgt_labels, rowmax, rowsum, rowS_acc, rowSP_acc,
        ysum_acc, xypart, sypart, out);
}

// Round 15
// 203.492 us; speedup vs baseline: 1.0599x; 1.0163x over previous
//
#include <hip/hip_runtime.h>
#include <math.h>

#define N_ROWS 400      // bs*Q
#define M_ROWS 80       // = 5*16
#define K_CLS  134
#define PN     12544    // = 49*256 selected points (exact!)
#define PFULL  65536    // 256*256
#define WORDS  (PFULL / 32)   // 2048 bitmap words
#define NSUB   25       // 400/16 n-subtiles
#define KCG    49       // rank chunks of 256 (= gemm k-groups)
#define NM     (N_ROWS * M_ROWS)
#define CHUNK  8192     // elements per buildY block
#define CWORDS (CHUNK / 32)      // 256 bitmap words per chunk
#define CPB    (PFULL / CHUNK)   // 8 chunks per row
#define SPAN   64       // staged-word capacity (need ~42+-2.4; 64 = +9 sigma)
#define NIT    8        // SPAN*8/64 fixed phase-1 iterations per row

typedef __attribute__((ext_vector_type(4))) float  f32x4;
typedef __attribute__((ext_vector_type(8))) __bf16 bf16x8;

__device__ __forceinline__ float wave_reduce_sum(float v) {
#pragma unroll
    for (int off = 32; off > 0; off >>= 1) v += __shfl_down(v, off, 64);
    return v;
}

// --- block 0: selection bitmap + per-word rank prefix + chunk-start words
//     cw[kc] (word containing rank 256*kc) + zero accumulators.
//     blocks 1..25: softmax stats (16 rows each, one per wave). ---
__global__ __launch_bounds__(1024) void sort_softmax_kernel(
        const int* __restrict__ point_idx,
        unsigned int* __restrict__ bitmap_g, int* __restrict__ rank_g,
        int* __restrict__ cw_g,
        float* __restrict__ rowS_acc, float* __restrict__ rowSP_acc,
        float* __restrict__ ysum_acc,
        const float* __restrict__ pred_logits,
        float* __restrict__ rowmax, float* __restrict__ rowsum) {
    int tid = threadIdx.x;
    if (blockIdx.x == 0) {
        __shared__ unsigned int bits[WORDS];   // 8 KB
        __shared__ int wtot[16], wbase[16];
        bits[tid] = 0u; bits[tid + 1024] = 0u;
        if (tid < N_ROWS) { rowS_acc[tid] = 0.f; rowSP_acc[tid] = 0.f; }
        if (tid < M_ROWS) ysum_acc[tid] = 0.f;
        __syncthreads();
        for (int i = tid; i < PN; i += 1024) {
            int p = point_idx[i];
            atomicOr(&bits[p >> 5], 1u << (p & 31));
        }
        __syncthreads();
        unsigned int w0 = bits[tid * 2], w1 = bits[tid * 2 + 1];
        int c0 = __popc(w0), c1 = __popc(w1);
        int cnt = c0 + c1;
        int lane = tid & 63, wid = tid >> 6;
        int v = cnt;
#pragma unroll
        for (int off = 1; off < 64; off <<= 1) {
            int u = __shfl_up(v, off, 64);
            if (lane >= off) v += u;
        }
        if (lane == 63) wtot[wid] = v;
        __syncthreads();
        if (tid == 0) {
            int run = 0;
#pragma unroll
            for (int i = 0; i < 16; ++i) { wbase[i] = run; run += wtot[i]; }
        }
        __syncthreads();
        int base = wbase[wid] + (v - cnt);          // exclusive rank before word 2*tid
        bitmap_g[tid * 2]     = w0;
        bitmap_g[tid * 2 + 1] = w1;
        rank_g[tid * 2]       = base;
        rank_g[tid * 2 + 1]   = base + c0;
        // chunk-start words: boundary rank kc*256 falling inside this word
        {
            int rb = base, c = c0, w = tid * 2;
            int kc = (rb + 255) >> 8;
            if (c > 0 && kc < KCG && kc * 256 < rb + c) cw_g[kc] = w;
        }
        {
            int rb = base + c0, c = c1, w = tid * 2 + 1;
            int kc = (rb + 255) >> 8;
            if (c > 0 && kc < KCG && kc * 256 < rb + c) cw_g[kc] = w;
        }
    } else {
        int wave = tid >> 6, lane = tid & 63;
        int n = (blockIdx.x - 1) * 16 + wave;       // < 400
        const float* row = pred_logits + n * K_CLS;
        float mx = -1e30f;
        for (int k = lane; k < K_CLS; k += 64) mx = fmaxf(mx, row[k]);
#pragma unroll
        for (int off = 32; off > 0; off >>= 1) mx = fmaxf(mx, __shfl_down(mx, off, 64));
        mx = __shfl(mx, 0, 64);
        float se = 0.f;
        for (int k = lane; k < K_CLS; k += 64) se += expf(row[k] - mx);
        se = wave_reduce_sum(se);
        if (lane == 0) { rowmax[n] = mx; rowsum[n] = se; }
    }
}

// --- buildY: compact tgt_masks into dense Yc[m][k] bf16. Branch-free
//     LDS rank-scatter (trash-slot redirect, unconditional ds_write). ---
__global__ __launch_bounds__(256) void buildY_kernel(
        const float* __restrict__ tgt_masks,
        const unsigned int* __restrict__ bitmap_g, const int* __restrict__ rank_g,
        __bf16* __restrict__ Yc, float* __restrict__ ysum_acc) {
    __shared__ __bf16 comp[CHUNK + 16];       // 16 KB + trash slots
    __shared__ unsigned int sb[CWORDS];       // 1 KB
    __shared__ int swb[CWORDS];               // 1 KB
    __shared__ float a0[4];
    int b   = blockIdx.x;
    int m = b / CPB, ch = b % CPB;
    int tid = threadIdx.x;
    int wave = tid >> 6, lane = tid & 63;
    int w0  = ch * CWORDS;
    int gb  = rank_g[w0];
    int end = (w0 + CWORDS == WORDS) ? PN : rank_g[w0 + CWORDS];
    int cnt = end - gb;
    sb[tid]  = bitmap_g[w0 + tid];
    swb[tid] = rank_g[w0 + tid] - gb;
    __syncthreads();
    const float* src = tgt_masks + (size_t)m * PFULL + ch * CHUNK;
    int t = CHUNK + (lane & 15);
#pragma unroll
    for (int it = 0; it < CHUNK / (256 * 4); ++it) {
        int e = (it * 256 + tid) * 4;
        f32x4 v = *(const f32x4*)(src + e);
        unsigned int w = sb[e >> 5];
        int bp = e & 31;
        int rb = swb[e >> 5] + __popc(w & ((1u << bp) - 1u));
        unsigned int m4 = (w >> bp) & 0xFu;
        int r0 = (m4 & 1u) ? rb : t;
        int r1 = (m4 & 2u) ? rb + (int)(m4 & 1u) : t;
        int r2 = (m4 & 4u) ? rb + __popc(m4 & 3u) : t;
        int r3 = (m4 & 8u) ? rb + __popc(m4 & 7u) : t;
        comp[r0] = (__bf16)((v[0] > 0.5f) ? 1.f : 0.f);
        comp[r1] = (__bf16)((v[1] > 0.5f) ? 1.f : 0.f);
        comp[r2] = (__bf16)((v[2] > 0.5f) ? 1.f : 0.f);
        comp[r3] = (__bf16)((v[3] > 0.5f) ? 1.f : 0.f);
    }
    __syncthreads();
    __bf16* yrow = Yc + (size_t)m * PN + gb;
    float ys = 0.f;
    for (int i = tid; i < cnt; i += 256) {
        __bf16 y = comp[i];
        yrow[i] = y;
        ys += (float)y;
    }
    ys = wave_reduce_sum(ys);
    if (lane == 0) a0[wave] = ys;
    __syncthreads();
    if (tid == 0)
        atomicAdd(&ysum_acc[m], a0[0] + a0[1] + a0[2] + a0[3]);
}

// --- fused gather+GEMM, round-15: phase 1 processes row PAIRS (16 loads
//     per pass) with a sched_barrier(0) fence between the load block and
//     the scatter block -- the compiler may NOT sink loads to their uses,
//     so 16 KB/wave stays in flight (fix for the round-7 de-pipelining).
//     Decode (bitmap/rank/popc) computed once per pair. ---
__global__ __launch_bounds__(256) void gemm_fused_kernel(
        const float* __restrict__ pred_masks,
        const __bf16* __restrict__ Yc,
        const unsigned int* __restrict__ bitmap_g,
        const int* __restrict__ rank_g, const int* __restrict__ cw_g,
        float* __restrict__ xypart, float* __restrict__ sypart,
        float* __restrict__ rowS_acc, float* __restrict__ rowSP_acc) {
    __shared__ __align__(16) unsigned char smem[20992];
    __bf16* comp      = (__bf16*)smem;                 // [16][272] = 8704 B
    unsigned int* sw  = (unsigned int*)(smem + 8704);  // 256 B
    int* sr           = (int*)(smem + 8960);           // 256 B
    float (*red)[20][64] = (float (*)[20][64])smem;    // 20480 B (aliases comp)
    float (*rowred)[2][16] = (float (*)[2][16])(smem + 20480);  // 512 B (no alias)

    int tid = threadIdx.x;
    int wave = tid >> 6, lane = tid & 63;
    int colL = lane & 15, quad = lane >> 4;
    int nsub = blockIdx.x % NSUB, kcg = blockIdx.x / NSUB;  // nsub fastest
    int n0 = nsub * 16;
    int wlo = cw_g[kcg];
    int ew  = (kcg == KCG - 1) ? (WORDS - 1) : cw_g[kcg + 1];
    int S = ew - wlo + 1; if (S > SPAN) S = SPAN;
    int E4 = S * 8;                           // valid f32x4 groups in span
    int rbase = kcg * 256;
    for (int i = tid; i < S; i += 256) {
        sw[i] = bitmap_g[wlo + i];
        sr[i] = rank_g[wlo + i] - rbase;      // local rank (can be negative)
    }
    // B loads up-front: latency hides under the phase-1 stream
    bf16x8 Bb[2][5];
#pragma unroll
    for (int i = 0; i < 2; ++i) {
        int k0 = kcg * 256 + (wave * 2 + i) * 32 + quad * 8;
#pragma unroll
        for (int j = 0; j < 5; ++j)
            Bb[i][j] = *(const bf16x8*)(Yc + (size_t)(16 * j + colL) * PN + k0);
    }
    __syncthreads();

    // ---- phase 1: branch-free scatter, row-pair passes, pinned loads ----
    int trash = 256 + (lane & 15);
#pragma unroll 1
    for (int rp = 0; rp < 2; ++rp) {
        int rowA = wave + rp * 8;             // {wave, wave+8}
        int rowB = rowA + 4;                  // {wave+4, wave+12}
        const float* srcA = pred_masks + (size_t)(n0 + rowA) * PFULL + (size_t)wlo * 32;
        const float* srcB = pred_masks + (size_t)(n0 + rowB) * PFULL + (size_t)wlo * 32;
        __bf16* crowA = comp + rowA * 272;
        __bf16* crowB = comp + rowB * 272;
        f32x4 va[NIT], vb2[NIT];
#pragma unroll
        for (int it = 0; it < NIT; ++it) {    // 16 loads, issued back-to-back
            int e4 = lane + it * 64;
            int e4c = (e4 < E4) ? e4 : (E4 - 1);   // clamp: duplicate = idempotent
            va[it]  = *(const f32x4*)(srcA + (size_t)e4c * 4);
            vb2[it] = *(const f32x4*)(srcB + (size_t)e4c * 4);
        }
        __builtin_amdgcn_sched_barrier(0);    // loads may NOT sink below here
#pragma unroll
        for (int it = 0; it < NIT; ++it) {
            int e4 = lane + it * 64;
            int e4c = (e4 < E4) ? e4 : (E4 - 1);
            unsigned int w = sw[e4c >> 3];
            int bp = (e4c & 7) * 4;
            int rb = sr[e4c >> 3] + __popc(w & ((1u << bp) - 1u));
            unsigned int m4 = (w >> bp) & 0xFu;
            int r0 = rb;
            int r1 = rb + (int)(m4 & 1u);
            int r2 = rb + __popc(m4 & 3u);
            int r3 = rb + __popc(m4 & 7u);
            r0 = ((m4 & 1u) && (unsigned)r0 < 256u) ? r0 : trash;
            r1 = ((m4 & 2u) && (unsigned)r1 < 256u) ? r1 : trash;
            r2 = ((m4 & 4u) && (unsigned)r2 < 256u) ? r2 : trash;
            r3 = ((m4 & 8u) && (unsigned)r3 < 256u) ? r3 : trash;
            crowA[r0] = (__bf16)va[it][0];
            crowA[r1] = (__bf16)va[it][1];
            crowA[r2] = (__bf16)va[it][2];
            crowA[r3] = (__bf16)va[it][3];
            crowB[r0] = (__bf16)vb2[it][0];
            crowB[r1] = (__bf16)vb2[it][1];
            crowB[r2] = (__bf16)vb2[it][2];
            crowB[r3] = (__bf16)vb2[it][3];
        }
    }
    __syncthreads();

    // ---- phase 2: A-frags from LDS, sigmoid/softplus, MFMA ----
    f32x4 accX[5], accS[5];
    f32x4 zero = {0.f, 0.f, 0.f, 0.f};
#pragma unroll
    for (int j = 0; j < 5; ++j) { accX[j] = zero; accS[j] = zero; }
    float sS = 0.f, sSP = 0.f;
#pragma unroll
    for (int i = 0; i < 2; ++i) {
        int kl = (wave * 2 + i) * 32 + quad * 8;
        bf16x8 aX = *(const bf16x8*)&comp[colL * 272 + kl];
        bf16x8 aSg;
#pragma unroll
        for (int jj = 0; jj < 8; ++jj) {
            float x  = (float)aX[jj];
            float ax = fabsf(x);
            float ee = __expf(-ax);
            float den = 1.f + ee;
            float inv = __builtin_amdgcn_rcpf(den);
            float sig = (x >= 0.f) ? inv : ee * inv;
            float sp  = fmaxf(x, 0.f) + __logf(den);
            aSg[jj] = (__bf16)sig;
            sS += sig; sSP += sp;
        }
#pragma unroll
        for (int j = 0; j < 5; ++j) {
            accX[j] = __builtin_amdgcn_mfma_f32_16x16x32_bf16(aX,  Bb[i][j], accX[j], 0, 0, 0);
            accS[j] = __builtin_amdgcn_mfma_f32_16x16x32_bf16(aSg, Bb[i][j], accS[j], 0, 0, 0);
        }
    }
    // row sums: lanes {colL, colL+16, colL+32, colL+48} hold row colL's parts
    sS  += __shfl_down(sS, 32, 64);
    sS  += __shfl_down(sS, 16, 64);
    sSP += __shfl_down(sSP, 32, 64);
    sSP += __shfl_down(sSP, 16, 64);
    if (lane < 16) { rowred[wave][0][lane] = sS; rowred[wave][1][lane] = sSP; }
    __syncthreads();   // all comp reads done -> red may now alias comp

    // ---- epilogue pass 1: xy partials + row-sum atomics ----
#pragma unroll
    for (int j = 0; j < 5; ++j)
#pragma unroll
        for (int r = 0; r < 4; ++r) red[wave][j * 4 + r][lane] = accX[j][r];
    __syncthreads();
#pragma unroll
    for (int v0 = 0; v0 < 5; ++v0) {
        int v = wave * 5 + v0;
        float s = red[0][v][lane] + red[1][v][lane] + red[2][v][lane] + red[3][v][lane];
        int j = v >> 2, r = v & 3;
        int n = n0 + quad * 4 + r, m = 16 * j + colL;   // verified C/D layout
        xypart[(size_t)kcg * NM + n * M_ROWS + m] = s;
    }
    if (tid < 16) {
        atomicAdd(&rowS_acc[n0 + tid],
                  rowred[0][0][tid] + rowred[1][0][tid] +
                  rowred[2][0][tid] + rowred[3][0][tid]);
    } else if (tid < 32) {
        int l = tid - 16;
        atomicAdd(&rowSP_acc[n0 + l],
                  rowred[0][1][l] + rowred[1][1][l] +
                  rowred[2][1][l] + rowred[3][1][l]);
    }
    __syncthreads();
    // ---- epilogue pass 2: sy partials ----
#pragma unroll
    for (int j = 0; j < 5; ++j)
#pragma unroll
        for (int r = 0; r < 4; ++r) red[wave][j * 4 + r][lane] = accS[j][r];
    __syncthreads();
#pragma unroll
    for (int v0 = 0; v0 < 5; ++v0) {
        int v = wave * 5 + v0;
        float s = red[0][v][lane] + red[1][v][lane] + red[2][v][lane] + red[3][v][lane];
        int j = v >> 2, r = v & 3;
        int n = n0 + quad * 4 + r, m = 16 * j + colL;
        sypart[(size_t)kcg * NM + n * M_ROWS + m] = s;
    }
}

// --- combine: reduce 49 xy/sy partials (4 lane-groups) + cost terms. ---
__global__ __launch_bounds__(256) void combine_kernel(
        const float* __restrict__ logits,
        const int* __restrict__ tgt_labels,
        const float* __restrict__ rowmax,
        const float* __restrict__ rowsum,
        const float* __restrict__ rowS_acc,
        const float* __restrict__ rowSP_acc,
        const float* __restrict__ ysum_acc,
        const float* __restrict__ xypart,
        const float* __restrict__ sypart,
        float* __restrict__ out) {
    __shared__ float sxy[4][64], ssy[4][64];
    int il = threadIdx.x & 63, q = threadIdx.x >> 6;
    int idx = blockIdx.x * 64 + il;
    int n = idx / M_ROWS, m = idx % M_ROWS;
    float xy = 0.f, sy = 0.f;
    for (int g = q; g < KCG; g += 4) {
        xy += xypart[(size_t)g * NM + idx];
        sy += sypart[(size_t)g * NM + idx];
    }
    sxy[q][il] = xy; ssy[q][il] = sy;
    __syncthreads();
    if (q == 0) {
        xy = sxy[0][il] + sxy[1][il] + sxy[2][il] + sxy[3][il];
        sy = ssy[0][il] + ssy[1][il] + ssy[2][il] + ssy[3][il];
        float ss = rowS_acc[n], sp = rowSP_acc[n], ysum = ysum_acc[m];
        int tc = tgt_labels[m];
        tc = min(max(tc, 0), K_CLS - 1);
        float p = expf(logits[n * K_CLS + tc] - rowmax[n]) / rowsum[n];
        float cost_class = -p;
        float cost_mask = (sp - xy) * (1.0f / PN);
        float cost_dice = 1.f - (2.f * sy + 1.f) / (ss + ysum + 1.f);
        out[idx] = 2.f * cost_class + 5.f * cost_mask + 5.f * cost_dice;
    }
}

extern "C" void kernel_launch(void* const* d_in, const int* in_sizes, int n_in,
                              void* d_out, int out_size, void* d_ws, size_t ws_size,
                              hipStream_t stream) {
    const float* pred_logits = (const float*)d_in[0];   // (4,100,134)
    const float* pred_masks  = (const float*)d_in[1];   // (4,100,256,256)
    const int*   tgt_labels  = (const int*)d_in[2];     // (80,)
    const float* tgt_masks   = (const float*)d_in[3];   // (80,256,256)
    const int*   point_idx   = (const int*)d_in[4];     // (12544,)
    float* out = (float*)d_out;                         // (4,100,80)

    char* ws = (char*)d_ws;
    size_t off = 0;
    auto carve = [&](size_t nbytes) {
        char* p = ws + off;
        off += (nbytes + 255) & ~(size_t)255;
        return p;
    };
    // accumulators zeroed by sort kernel (stream-ordered before users)
    unsigned int* bitmap = (unsigned int*)carve(WORDS * 4);            // 8 KB
    int*   rankp  = (int*)carve(WORDS * 4);                            // 8 KB
    int*   cw     = (int*)carve(KCG * 4);
    float* rowmax = (float*)carve(N_ROWS * 4);
    float* rowsum = (float*)carve(N_ROWS * 4);
    float* rowS_acc  = (float*)carve(N_ROWS * 4);
    float* rowSP_acc = (float*)carve(N_ROWS * 4);
    float* ysum_acc  = (float*)carve(M_ROWS * 4);
    __bf16* Yc = (__bf16*)carve((size_t)M_ROWS * PN * 2);              // 2.0 MB
    float* xypart = (float*)carve((size_t)KCG * NM * 4);               // 6.3 MB
    float* sypart = (float*)carve((size_t)KCG * NM * 4);               // 6.3 MB
    (void)ws_size; (void)in_sizes; (void)n_in; (void)out_size;

    sort_softmax_kernel<<<26, 1024, 0, stream>>>(
        point_idx, bitmap, rankp, cw, rowS_acc, rowSP_acc, ysum_acc,
        pred_logits, rowmax, rowsum);
    buildY_kernel<<<M_ROWS * CPB, 256, 0, stream>>>(
        tgt_masks, bitmap, rankp, Yc, ysum_acc);
    gemm_fused_kernel<<<NSUB * KCG, 256, 0, stream>>>(
        pred_masks, Yc, bitmap, rankp, cw, xypart, sypart,
        rowS_acc, rowSP_acc);
    combine_kernel<<<NM / 64, 256, 0, stream>>>(
        pred_logits, tgt_labels, rowmax, rowsum, rowS_acc, rowSP_acc,
        ysum_acc, xypart, sypart, out);
}

// Round 16
// 202.579 us; speedup vs baseline: 1.0646x; 1.0045x over previous
//
#include <hip/hip_runtime.h>
#include <math.h>

#define N_ROWS 400      // bs*Q
#define M_ROWS 80       // = 5*16
#define K_CLS  134
#define PN     12544    // = 49*256 selected points (exact!)
#define PFULL  65536    // 256*256
#define WORDS  (PFULL / 32)   // 2048 bitmap words
#define NSUB   25       // 400/16 n-subtiles
#define KCG    49       // rank chunks of 256 (= gemm k-groups)
#define NM     (N_ROWS * M_ROWS)
#define CHUNK  8192     // elements per buildY block
#define CWORDS (CHUNK / 32)      // 256 bitmap words per chunk
#define CPB    (PFULL / CHUNK)   // 8 chunks per row
#define SPAN   64       // staged-word capacity (need ~42+-2.4; 64 = +9 sigma)
#define NIT    8        // SPAN*8/64 fixed phase-1 iterations per row

typedef __attribute__((ext_vector_type(4))) float  f32x4;
typedef __attribute__((ext_vector_type(8))) __bf16 bf16x8;

__device__ __forceinline__ float wave_reduce_sum(float v) {
#pragma unroll
    for (int off = 32; off > 0; off >>= 1) v += __shfl_down(v, off, 64);
    return v;
}

// --- block 0: selection bitmap + per-word rank prefix + chunk-start words
//     cw[kc] (word containing rank 256*kc) + zero accumulators.
//     blocks 1..25: softmax stats (16 rows each, one per wave). ---
__global__ __launch_bounds__(1024) void sort_softmax_kernel(
        const int* __restrict__ point_idx,
        unsigned int* __restrict__ bitmap_g, int* __restrict__ rank_g,
        int* __restrict__ cw_g,
        float* __restrict__ rowS_acc, float* __restrict__ rowSP_acc,
        float* __restrict__ ysum_acc,
        const float* __restrict__ pred_logits,
        float* __restrict__ rowmax, float* __restrict__ rowsum) {
    int tid = threadIdx.x;
    if (blockIdx.x == 0) {
        __shared__ unsigned int bits[WORDS];   // 8 KB
        __shared__ int wtot[16], wbase[16];
        bits[tid] = 0u; bits[tid + 1024] = 0u;
        if (tid < N_ROWS) { rowS_acc[tid] = 0.f; rowSP_acc[tid] = 0.f; }
        if (tid < M_ROWS) ysum_acc[tid] = 0.f;
        __syncthreads();
        for (int i = tid; i < PN; i += 1024) {
            int p = point_idx[i];
            atomicOr(&bits[p >> 5], 1u << (p & 31));
        }
        __syncthreads();
        unsigned int w0 = bits[tid * 2], w1 = bits[tid * 2 + 1];
        int c0 = __popc(w0), c1 = __popc(w1);
        int cnt = c0 + c1;
        int lane = tid & 63, wid = tid >> 6;
        int v = cnt;
#pragma unroll
        for (int off = 1; off < 64; off <<= 1) {
            int u = __shfl_up(v, off, 64);
            if (lane >= off) v += u;
        }
        if (lane == 63) wtot[wid] = v;
        __syncthreads();
        if (tid == 0) {
            int run = 0;
#pragma unroll
            for (int i = 0; i < 16; ++i) { wbase[i] = run; run += wtot[i]; }
        }
        __syncthreads();
        int base = wbase[wid] + (v - cnt);          // exclusive rank before word 2*tid
        bitmap_g[tid * 2]     = w0;
        bitmap_g[tid * 2 + 1] = w1;
        rank_g[tid * 2]       = base;
        rank_g[tid * 2 + 1]   = base + c0;
        // chunk-start words: boundary rank kc*256 falling inside this word
        {
            int rb = base, c = c0, w = tid * 2;
            int kc = (rb + 255) >> 8;
            if (c > 0 && kc < KCG && kc * 256 < rb + c) cw_g[kc] = w;
        }
        {
            int rb = base + c0, c = c1, w = tid * 2 + 1;
            int kc = (rb + 255) >> 8;
            if (c > 0 && kc < KCG && kc * 256 < rb + c) cw_g[kc] = w;
        }
    } else {
        int wave = tid >> 6, lane = tid & 63;
        int n = (blockIdx.x - 1) * 16 + wave;       // < 400
        const float* row = pred_logits + n * K_CLS;
        float mx = -1e30f;
        for (int k = lane; k < K_CLS; k += 64) mx = fmaxf(mx, row[k]);
#pragma unroll
        for (int off = 32; off > 0; off >>= 1) mx = fmaxf(mx, __shfl_down(mx, off, 64));
        mx = __shfl(mx, 0, 64);
        float se = 0.f;
        for (int k = lane; k < K_CLS; k += 64) se += expf(row[k] - mx);
        se = wave_reduce_sum(se);
        if (lane == 0) { rowmax[n] = mx; rowsum[n] = se; }
    }
}

// --- buildY: compact tgt_masks into dense Yc[m][k] bf16. Branch-free
//     LDS rank-scatter (trash-slot redirect, unconditional ds_write). ---
__global__ __launch_bounds__(256) void buildY_kernel(
        const float* __restrict__ tgt_masks,
        const unsigned int* __restrict__ bitmap_g, const int* __restrict__ rank_g,
        __bf16* __restrict__ Yc, float* __restrict__ ysum_acc) {
    __shared__ __bf16 comp[CHUNK + 16];       // 16 KB + trash slots
    __shared__ unsigned int sb[CWORDS];       // 1 KB
    __shared__ int swb[CWORDS];               // 1 KB
    __shared__ float a0[4];
    int b   = blockIdx.x;
    int m = b / CPB, ch = b % CPB;
    int tid = threadIdx.x;
    int wave = tid >> 6, lane = tid & 63;
    int w0  = ch * CWORDS;
    int gb  = rank_g[w0];
    int end = (w0 + CWORDS == WORDS) ? PN : rank_g[w0 + CWORDS];
    int cnt = end - gb;
    sb[tid]  = bitmap_g[w0 + tid];
    swb[tid] = rank_g[w0 + tid] - gb;
    __syncthreads();
    const float* src = tgt_masks + (size_t)m * PFULL + ch * CHUNK;
    int t = CHUNK + (lane & 15);
#pragma unroll
    for (int it = 0; it < CHUNK / (256 * 4); ++it) {
        int e = (it * 256 + tid) * 4;
        f32x4 v = *(const f32x4*)(src + e);
        unsigned int w = sb[e >> 5];
        int bp = e & 31;
        int rb = swb[e >> 5] + __popc(w & ((1u << bp) - 1u));
        unsigned int m4 = (w >> bp) & 0xFu;
        int r0 = (m4 & 1u) ? rb : t;
        int r1 = (m4 & 2u) ? rb + (int)(m4 & 1u) : t;
        int r2 = (m4 & 4u) ? rb + __popc(m4 & 3u) : t;
        int r3 = (m4 & 8u) ? rb + __popc(m4 & 7u) : t;
        comp[r0] = (__bf16)((v[0] > 0.5f) ? 1.f : 0.f);
        comp[r1] = (__bf16)((v[1] > 0.5f) ? 1.f : 0.f);
        comp[r2] = (__bf16)((v[2] > 0.5f) ? 1.f : 0.f);
        comp[r3] = (__bf16)((v[3] > 0.5f) ? 1.f : 0.f);
    }
    __syncthreads();
    __bf16* yrow = Yc + (size_t)m * PN + gb;
    float ys = 0.f;
    for (int i = tid; i < cnt; i += 256) {
        __bf16 y = comp[i];
        yrow[i] = y;
        ys += (float)y;
    }
    ys = wave_reduce_sum(ys);
    if (lane == 0) a0[wave] = ys;
    __syncthreads();
    if (tid == 0)
        atomicAdd(&ysum_acc[m], a0[0] + a0[1] + a0[2] + a0[3]);
}

// --- fused gather+GEMM, round-16: 8 waves/block. Phase 1 is a SINGLE
//     pass per wave (rows {w, w+8}, 16 pinned loads + sched_barrier);
//     phase 2 splits k 8 ways (one 32-k slice per wave, 10 MFMAs);
//     epilogue reduces over 8 waves (red[8][20][64], 40 KB). Halves the
//     per-block serial depth vs the 4-wave version. ---
__global__ __launch_bounds__(512, 2) void gemm_fused_kernel(
        const float* __restrict__ pred_masks,
        const __bf16* __restrict__ Yc,
        const unsigned int* __restrict__ bitmap_g,
        const int* __restrict__ rank_g, const int* __restrict__ cw_g,
        float* __restrict__ xypart, float* __restrict__ sypart,
        float* __restrict__ rowS_acc, float* __restrict__ rowSP_acc) {
    __shared__ __align__(16) unsigned char smem[41984];
    __bf16* comp      = (__bf16*)smem;                 // [16][272] = 8704 B
    unsigned int* sw  = (unsigned int*)(smem + 8704);  // 256 B
    int* sr           = (int*)(smem + 8960);           // 256 B
    float (*red)[20][64] = (float (*)[20][64])smem;    // 40960 B (aliases comp)
    float (*rowred)[2][16] = (float (*)[2][16])(smem + 40960);  // 1024 B (no alias)

    int tid = threadIdx.x;
    int wave = tid >> 6, lane = tid & 63;
    int colL = lane & 15, quad = lane >> 4;
    int nsub = blockIdx.x % NSUB, kcg = blockIdx.x / NSUB;  // nsub fastest
    int n0 = nsub * 16;
    int wlo = cw_g[kcg];
    int ew  = (kcg == KCG - 1) ? (WORDS - 1) : cw_g[kcg + 1];
    int S = ew - wlo + 1; if (S > SPAN) S = SPAN;
    int E4 = S * 8;                           // valid f32x4 groups in span
    int rbase = kcg * 256;
    for (int i = tid; i < S; i += 512) {
        sw[i] = bitmap_g[wlo + i];
        sr[i] = rank_g[wlo + i] - rbase;      // local rank (can be negative)
    }
    // B loads up-front: one 32-k slice per wave (hides under phase 1)
    bf16x8 Bb[5];
    {
        int k0 = rbase + wave * 32 + quad * 8;
#pragma unroll
        for (int j = 0; j < 5; ++j)
            Bb[j] = *(const bf16x8*)(Yc + (size_t)(16 * j + colL) * PN + k0);
    }
    __syncthreads();

    // ---- phase 1: single pass, wave owns rows {wave, wave+8}; pinned loads ----
    int trash = 256 + (lane & 15);
    {
        int rowA = wave, rowB = wave + 8;
        const float* srcA = pred_masks + (size_t)(n0 + rowA) * PFULL + (size_t)wlo * 32;
        const float* srcB = pred_masks + (size_t)(n0 + rowB) * PFULL + (size_t)wlo * 32;
        __bf16* crowA = comp + rowA * 272;
        __bf16* crowB = comp + rowB * 272;
        f32x4 va[NIT], vb2[NIT];
#pragma unroll
        for (int it = 0; it < NIT; ++it) {    // 16 loads, issued back-to-back
            int e4 = lane + it * 64;
            int e4c = (e4 < E4) ? e4 : (E4 - 1);   // clamp: duplicate = idempotent
            va[it]  = *(const f32x4*)(srcA + (size_t)e4c * 4);
            vb2[it] = *(const f32x4*)(srcB + (size_t)e4c * 4);
        }
        __builtin_amdgcn_sched_barrier(0);    // loads may NOT sink below here
#pragma unroll
        for (int it = 0; it < NIT; ++it) {
            int e4 = lane + it * 64;
            int e4c = (e4 < E4) ? e4 : (E4 - 1);
            unsigned int w = sw[e4c >> 3];
            int bp = (e4c & 7) * 4;
            int rb = sr[e4c >> 3] + __popc(w & ((1u << bp) - 1u));
            unsigned int m4 = (w >> bp) & 0xFu;
            int r0 = rb;
            int r1 = rb + (int)(m4 & 1u);
            int r2 = rb + __popc(m4 & 3u);
            int r3 = rb + __popc(m4 & 7u);
            r0 = ((m4 & 1u) && (unsigned)r0 < 256u) ? r0 : trash;
            r1 = ((m4 & 2u) && (unsigned)r1 < 256u) ? r1 : trash;
            r2 = ((m4 & 4u) && (unsigned)r2 < 256u) ? r2 : trash;
            r3 = ((m4 & 8u) && (unsigned)r3 < 256u) ? r3 : trash;
            crowA[r0] = (__bf16)va[it][0];
            crowA[r1] = (__bf16)va[it][1];
            crowA[r2] = (__bf16)va[it][2];
            crowA[r3] = (__bf16)va[it][3];
            crowB[r0] = (__bf16)vb2[it][0];
            crowB[r1] = (__bf16)vb2[it][1];
            crowB[r2] = (__bf16)vb2[it][2];
            crowB[r3] = (__bf16)vb2[it][3];
        }
    }
    __syncthreads();

    // ---- phase 2: one 32-k slice per wave; sigmoid/softplus; 10 MFMAs ----
    f32x4 accX[5], accS[5];
    f32x4 zero = {0.f, 0.f, 0.f, 0.f};
#pragma unroll
    for (int j = 0; j < 5; ++j) { accX[j] = zero; accS[j] = zero; }
    float sS = 0.f, sSP = 0.f;
    {
        int kl = wave * 32 + quad * 8;
        bf16x8 aX = *(const bf16x8*)&comp[colL * 272 + kl];
        bf16x8 aSg;
#pragma unroll
        for (int jj = 0; jj < 8; ++jj) {
            float x  = (float)aX[jj];
            float ax = fabsf(x);
            float ee = __expf(-ax);
            float den = 1.f + ee;
            float inv = __builtin_amdgcn_rcpf(den);
            float sig = (x >= 0.f) ? inv : ee * inv;
            float sp  = fmaxf(x, 0.f) + __logf(den);
            aSg[jj] = (__bf16)sig;
            sS += sig; sSP += sp;
        }
#pragma unroll
        for (int j = 0; j < 5; ++j) {
            accX[j] = __builtin_amdgcn_mfma_f32_16x16x32_bf16(aX,  Bb[j], accX[j], 0, 0, 0);
            accS[j] = __builtin_amdgcn_mfma_f32_16x16x32_bf16(aSg, Bb[j], accS[j], 0, 0, 0);
        }
    }
    // row sums: lanes {colL, colL+16, colL+32, colL+48} hold row colL's parts
    sS  += __shfl_down(sS, 32, 64);
    sS  += __shfl_down(sS, 16, 64);
    sSP += __shfl_down(sSP, 32, 64);
    sSP += __shfl_down(sSP, 16, 64);
    if (lane < 16) { rowred[wave][0][lane] = sS; rowred[wave][1][lane] = sSP; }
    __syncthreads();   // all comp reads done -> red may now alias comp

    // ---- epilogue pass 1: xy partials + row-sum atomics ----
#pragma unroll
    for (int j = 0; j < 5; ++j)
#pragma unroll
        for (int r = 0; r < 4; ++r) red[wave][j * 4 + r][lane] = accX[j][r];
    __syncthreads();
    for (int v = wave; v < 20; v += 8) {
        float s = red[0][v][lane] + red[1][v][lane] + red[2][v][lane] + red[3][v][lane]
                + red[4][v][lane] + red[5][v][lane] + red[6][v][lane] + red[7][v][lane];
        int j = v >> 2, r = v & 3;
        int n = n0 + quad * 4 + r, m = 16 * j + colL;   // verified C/D layout
        xypart[(size_t)kcg * NM + n * M_ROWS + m] = s;
    }
    if (tid < 16) {
        float s = 0.f;
#pragma unroll
        for (int w = 0; w < 8; ++w) s += rowred[w][0][tid];
        atomicAdd(&rowS_acc[n0 + tid], s);
    } else if (tid < 32) {
        int l = tid - 16;
        float s = 0.f;
#pragma unroll
        for (int w = 0; w < 8; ++w) s += rowred[w][1][l];
        atomicAdd(&rowSP_acc[n0 + l], s);
    }
    __syncthreads();
    // ---- epilogue pass 2: sy partials ----
#pragma unroll
    for (int j = 0; j < 5; ++j)
#pragma unroll
        for (int r = 0; r < 4; ++r) red[wave][j * 4 + r][lane] = accS[j][r];
    __syncthreads();
    for (int v = wave; v < 20; v += 8) {
        float s = red[0][v][lane] + red[1][v][lane] + red[2][v][lane] + red[3][v][lane]
                + red[4][v][lane] + red[5][v][lane] + red[6][v][lane] + red[7][v][lane];
        int j = v >> 2, r = v & 3;
        int n = n0 + quad * 4 + r, m = 16 * j + colL;
        sypart[(size_t)kcg * NM + n * M_ROWS + m] = s;
    }
}

// --- combine: reduce 49 xy/sy partials (4 lane-groups) + cost terms. ---
__global__ __launch_bounds__(256) void combine_kernel(
        const float* __restrict__ logits,
        const int* __restrict__ tgt_labels,
        const float* __restrict__ rowmax,
        const float* __restrict__ rowsum,
        const float* __restrict__ rowS_acc,
        const float* __restrict__ rowSP_acc,
        const float* __restrict__ ysum_acc,
        const float* __restrict__ xypart,
        const float* __restrict__ sypart,
        float* __restrict__ out) {
    __shared__ float sxy[4][64], ssy[4][64];
    int il = threadIdx.x & 63, q = threadIdx.x >> 6;
    int idx = blockIdx.x * 64 + il;
    int n = idx / M_ROWS, m = idx % M_ROWS;
    float xy = 0.f, sy = 0.f;
    for (int g = q; g < KCG; g += 4) {
        xy += xypart[(size_t)g * NM + idx];
        sy += sypart[(size_t)g * NM + idx];
    }
    sxy[q][il] = xy; ssy[q][il] = sy;
    __syncthreads();
    if (q == 0) {
        xy = sxy[0][il] + sxy[1][il] + sxy[2][il] + sxy[3][il];
        sy = ssy[0][il] + ssy[1][il] + ssy[2][il] + ssy[3][il];
        float ss = rowS_acc[n], sp = rowSP_acc[n], ysum = ysum_acc[m];
        int tc = tgt_labels[m];
        tc = min(max(tc, 0), K_CLS - 1);
        float p = expf(logits[n * K_CLS + tc] - rowmax[n]) / rowsum[n];
        float cost_class = -p;
        float cost_mask = (sp - xy) * (1.0f / PN);
        float cost_dice = 1.f - (2.f * sy + 1.f) / (ss + ysum + 1.f);
        out[idx] = 2.f * cost_class + 5.f * cost_mask + 5.f * cost_dice;
    }
}

extern "C" void kernel_launch(void* const* d_in, const int* in_sizes, int n_in,
                              void* d_out, int out_size, void* d_ws, size_t ws_size,
                              hipStream_t stream) {
    const float* pred_logits = (const float*)d_in[0];   // (4,100,134)
    const float* pred_masks  = (const float*)d_in[1];   // (4,100,256,256)
    const int*   tgt_labels  = (const int*)d_in[2];     // (80,)
    const float* tgt_masks   = (const float*)d_in[3];   // (80,256,256)
    const int*   point_idx   = (const int*)d_in[4];     // (12544,)
    float* out = (float*)d_out;                         // (4,100,80)

    char* ws = (char*)d_ws;
    size_t off = 0;
    auto carve = [&](size_t nbytes) {
        char* p = ws + off;
        off += (nbytes + 255) & ~(size_t)255;
        return p;
    };
    // accumulators zeroed by sort kernel (stream-ordered before users)
    unsigned int* bitmap = (unsigned int*)carve(WORDS * 4);            // 8 KB
    int*   rankp  = (int*)carve(WORDS * 4);                            // 8 KB
    int*   cw     = (int*)carve(KCG * 4);
    float* rowmax = (float*)carve(N_ROWS * 4);
    float* rowsum = (float*)carve(N_ROWS * 4);
    float* rowS_acc  = (float*)carve(N_ROWS * 4);
    float* rowSP_acc = (float*)carve(N_ROWS * 4);
    float* ysum_acc  = (float*)carve(M_ROWS * 4);
    __bf16* Yc = (__bf16*)carve((size_t)M_ROWS * PN * 2);              // 2.0 MB
    float* xypart = (float*)carve((size_t)KCG * NM * 4);               // 6.3 MB
    float* sypart = (float*)carve((size_t)KCG * NM * 4);               // 6.3 MB
    (void)ws_size; (void)in_sizes; (void)n_in; (void)out_size;

    sort_softmax_kernel<<<26, 1024, 0, stream>>>(
        point_idx, bitmap, rankp, cw, rowS_acc, rowSP_acc, ysum_acc,
        pred_logits, rowmax, rowsum);
    buildY_kernel<<<M_ROWS * CPB, 256, 0, stream>>>(
        tgt_masks, bitmap, rankp, Yc, ysum_acc);
    gemm_fused_kernel<<<NSUB * KCG, 512, 0, stream>>>(
        pred_masks, Yc, bitmap, rankp, cw, xypart, sypart,
        rowS_acc, rowSP_acc);
    combine_kernel<<<NM / 64, 256, 0, stream>>>(
        pred_logits, tgt_labels, rowmax, rowsum, rowS_acc, rowSP_acc,
        ysum_acc, xypart, sypart, out);
}